// Round 1
// baseline (773.164 us; speedup 1.0000x reference)
//
#include <hip/hip_runtime.h>
#include <math.h>

#define EPSF 1e-6f
#define NB   4
#define NC   3
#define HH   768
#define KS   31
#define KK   961
#define NHW  11
#define NN   121
#define NZ   14
#define HID  64

// workspace layout (float offsets)
#define XLIN_OFF  0
#define XLIN_SZ   (NB*NC*HH*HH)            // 7,077,888
#define BASIS_OFF (XLIN_OFF + XLIN_SZ)
#define MASK_OFF  (BASIS_OFF + 13456)      // basis needs 14*961=13454
#define COEF_OFF  (MASK_OFF + 964)         // mask needs 961
#define KERN_OFF  (COEF_OFF + 1696)        // coeffs need 121*14=1694
// kern needs 363*961 = 348,843 -> total ~29.8 MB

__device__ __forceinline__ float hann_f(int p) {
    return 0.5f * (1.0f - cosf(6.283185307179586f * (float)p / 128.0f));
}

__global__ void k_pow(const float* __restrict__ x, const float* __restrict__ gp,
                      float* __restrict__ y, int n) {
    float g = *gp;
    for (int i = blockIdx.x * blockDim.x + threadIdx.x; i < n; i += gridDim.x * blockDim.x)
        y[i] = powf(fmaxf(x[i], 0.0f) + EPSF, g);
}

// Zernike-like polynomial basis, bit-exact mask vs numpy linspace semantics.
__global__ void k_basis(float* __restrict__ ws) {
    __shared__ float red[256];
    __shared__ float srms[NZ];
    __shared__ float scnt;
    float* basis = ws + BASIS_OFF;
    float* mask  = ws + MASK_OFF;
    int tid = threadIdx.x;
    double lsq[NZ];
    #pragma unroll
    for (int z = 0; z < NZ; ++z) lsq[z] = 0.0;
    double lcnt = 0.0;
    for (int pix = tid; pix < KK; pix += 256) {
        int i = pix / 31, j = pix - i * 31;
        double x = (j == 30) ? 1.0 : (-1.0 + (double)j * (2.0 / 30.0));
        double y = (i == 30) ? 1.0 : (-1.0 + (double)i * (2.0 / 30.0));
        double r2 = x * x + y * y;
        float m = (r2 <= 1.0) ? 1.0f : 0.0f;
        mask[pix] = m;
        lcnt += (double)m;
        #pragma unroll
        for (int deg = 1; deg <= 4; ++deg) {
            #pragma unroll
            for (int ii = 0; ii <= deg; ++ii) {
                const int z = deg * (deg + 1) / 2 - 1 + ii;
                double px = 1.0, py = 1.0;
                #pragma unroll
                for (int t = 0; t < deg - ii; ++t) px *= x;
                #pragma unroll
                for (int t = 0; t < ii; ++t) py *= y;
                float bf = (float)(px * py) * m;
                basis[z * KK + pix] = bf;
                lsq[z] += (double)bf * (double)bf;
            }
        }
    }
    for (int q = 0; q < NZ + 1; ++q) {
        red[tid] = (q < NZ) ? (float)lsq[q] : (float)lcnt;
        __syncthreads();
        for (int s = 128; s > 0; s >>= 1) {
            if (tid < s) red[tid] += red[tid + s];
            __syncthreads();
        }
        if (tid == 0) { if (q < NZ) srms[q] = red[0]; else scnt = red[0]; }
        __syncthreads();
    }
    if (tid < NZ) srms[tid] = sqrtf(srms[tid] / scnt) + 1e-8f;
    __syncthreads();
    for (int pix = tid; pix < KK; pix += 256) {
        #pragma unroll
        for (int z = 0; z < NZ; ++z)
            basis[z * KK + pix] = basis[z * KK + pix] / srms[z];
    }
}

// 121 unique coords (batch-tiled in reference), one block of 64 per coord.
__global__ void k_mlp(const float* __restrict__ w1, const float* __restrict__ b1,
                      const float* __restrict__ w2, const float* __restrict__ b2,
                      const float* __restrict__ w3, const float* __restrict__ b3,
                      float* __restrict__ ws) {
    __shared__ float h1[HID], h2[HID];
    int n = blockIdx.x, t = threadIdx.x;
    int a = n / NHW, bw = n - a * NHW;
    float gy = (float)((((double)(a * 64)  + 64.0) / 768.0) * 2.0 - 1.0);
    float gx = (float)((((double)(bw * 64) + 64.0) / 768.0) * 2.0 - 1.0);
    h1[t] = tanhf(gy * w1[t] + gx * w1[HID + t] + b1[t]);
    __syncthreads();
    float acc2 = b2[t];
    for (int k = 0; k < HID; ++k) acc2 += h1[k] * w2[k * HID + t];
    h2[t] = tanhf(acc2);
    __syncthreads();
    if (t < NZ) {
        float acc3 = b3[t];
        for (int k = 0; k < HID; ++k) acc3 += h2[k] * w3[k * NZ + t];
        ws[COEF_OFF + n * NZ + t] = acc3;
    }
}

// One block per (n,c): phase -> field -> 31-pt row DFT -> col DFT -> |F|^2,
// normalize, write with fftshift+flip folded: kflip[u,v]=|F[(15-u)%31,(15-v)%31]|^2/sum
__global__ void k_psf(float* __restrict__ ws) {
    __shared__ float fre[KK], fim[KK], gre[KK], gim[KK], sS[KK];
    __shared__ float twc[KS], tws[KS], cf[NZ], red[128];
    int blk = blockIdx.x;
    int n = blk / 3, c = blk - n * 3;
    int tid = threadIdx.x;
    const float* basis = ws + BASIS_OFF;
    const float* mask  = ws + MASK_OFF;
    if (tid < NZ) cf[tid] = ws[COEF_OFF + n * NZ + tid];
    if (tid < KS) {
        float ang = -6.283185307179586f * (float)tid / 31.0f;
        float s, co;
        sincosf(ang, &s, &co);
        twc[tid] = co; tws[tid] = s;
    }
    const float wl = (c == 0) ? (0.53f / 0.61f) : ((c == 1) ? 1.0f : (0.53f / 0.47f));
    __syncthreads();
    for (int pix = tid; pix < KK; pix += 128) {
        float ph = 0.0f;
        #pragma unroll
        for (int z = 0; z < NZ; ++z) ph += cf[z] * basis[z * KK + pix];
        float ang = 6.283185307179586f * (wl * ph);
        float s, co;
        sincosf(ang, &s, &co);
        float m = mask[pix];
        fre[pix] = m * co;
        fim[pix] = m * s;
    }
    __syncthreads();
    for (int pix = tid; pix < KK; pix += 128) {
        int i = pix / 31, q = pix - i * 31;
        float ar = 0.0f, ai = 0.0f;
        int m = 0;
        const float* br = &fre[i * 31];
        const float* bi = &fim[i * 31];
        #pragma unroll
        for (int j = 0; j < 31; ++j) {
            float tc = twc[m], ts = tws[m];
            float xr = br[j], xi = bi[j];
            ar += xr * tc - xi * ts;
            ai += xr * ts + xi * tc;
            m += q; if (m >= 31) m -= 31;
        }
        gre[pix] = ar; gim[pix] = ai;
    }
    __syncthreads();
    float lsum = 0.0f;
    for (int pix = tid; pix < KK; pix += 128) {
        int p = pix / 31, q = pix - p * 31;
        float ar = 0.0f, ai = 0.0f;
        int m = 0;
        #pragma unroll
        for (int i2 = 0; i2 < 31; ++i2) {
            float tc = twc[m], ts = tws[m];
            float xr = gre[i2 * 31 + q], xi = gim[i2 * 31 + q];
            ar += xr * tc - xi * ts;
            ai += xr * ts + xi * tc;
            m += p; if (m >= 31) m -= 31;
        }
        float sv = ar * ar + ai * ai;
        sS[pix] = sv;
        lsum += sv;
    }
    red[tid] = lsum;
    __syncthreads();
    for (int s = 64; s > 0; s >>= 1) {
        if (tid < s) red[tid] += red[tid + s];
        __syncthreads();
    }
    float tot = red[0] + EPSF;
    float* kern = ws + KERN_OFF + (n * 3 + c) * KK;
    for (int pix = tid; pix < KK; pix += 128) {
        int u = pix / 31, v = pix - u * 31;
        int iu = 15 - u; if (iu < 0) iu += 31;
        int iv = 15 - v; if (iv < 0) iv += 31;
        kern[pix] = sS[iu * 31 + iv] / tot;
    }
}

// Hot kernel: per (bn,c) unit x 4 row-blocks. Block tile 32 rows x 128 cols,
// wave tile 16 rows x 64 cols (lane = column -> stride-1 conflict-free LDS).
// Per v-step: 46 vector LDS reads feed 496 FMAs (~10.8 FMA/read).
__global__ __launch_bounds__(256) void k_conv(const float* __restrict__ ws,
                                              float* __restrict__ out) {
    __shared__ float sK[KK];
    __shared__ float sP[62][160];
    int unit = blockIdx.x;
    int rb = blockIdx.y;
    int bn = unit / 3, c = unit - bn * 3;
    int b = bn / NN, n = bn - b * NN;
    int a = n / NHW, bw = n - a * NHW;
    int tid = threadIdx.x;
    const float* kern = ws + KERN_OFF + (n * 3 + c) * KK;
    for (int i = tid; i < KK; i += 256) sK[i] = kern[i];
    const float* xl = ws + XLIN_OFF + (b * 3 + c) * (HH * HH);
    int row0 = rb * 32;   // output-row base; LDS slab = zero-padded patch rows row0..row0+61
    for (int idx = tid; idx < 62 * 158; idx += 256) {
        int s = idx / 158, pc = idx - s * 158;
        int pi = row0 + s - 15;   // patch-local row (zero-pad outside [0,128))
        int pj = pc - 15;
        float v = 0.0f;
        if (pi >= 0 && pi < 128 && pj >= 0 && pj < 128)
            v = xl[(a * 64 + pi) * HH + (bw * 64 + pj)];
        sP[s][pc] = v;
    }
    __syncthreads();
    int wave = tid >> 6, lane = tid & 63;
    int wr = (wave >> 1) * 16;    // wave's output-row offset within block (0|16)
    int c0 = (wave & 1) * 64;     // wave's column base (0|64)
    int col = c0 + lane;
    float acc[16];
    #pragma unroll
    for (int r = 0; r < 16; ++r) acc[r] = 0.0f;
    const float* pbase = &sP[wr][col];
    #pragma unroll 1
    for (int v = 0; v < 31; ++v) {
        float w[46];
        #pragma unroll
        for (int s = 0; s < 46; ++s) w[s] = pbase[s * 160 + v];
        #pragma unroll
        for (int u = 0; u < 31; ++u) {
            float kv = sK[u * 31 + v];   // wave-uniform broadcast
            #pragma unroll
            for (int r = 0; r < 16; ++r) acc[r] += kv * w[u + r];
        }
    }
    float wcol = hann_f(col);
    float* ob = out + (b * 3 + c) * (HH * HH) + (a * 64) * HH + bw * 64 + col;
    #pragma unroll
    for (int r = 0; r < 16; ++r) {
        int i = row0 + wr + r;
        atomicAdd(ob + i * HH, acc[r] * hann_f(i) * wcol);
    }
}

// Overlap-add normalization (norm is separable: sh[y]*sw[x]) + inverse gamma.
__global__ void k_final(float* __restrict__ out, const float* __restrict__ gp, int ntot) {
    float ig = 1.0f / (*gp);
    for (int idx = blockIdx.x * blockDim.x + threadIdx.x; idx < ntot;
         idx += gridDim.x * blockDim.x) {
        int x = idx % HH;
        int y = (idx / HH) % HH;
        int ay = y >> 6, ry = y - (ay << 6);
        float sh = 0.0f;
        if (ay <= 10) sh += hann_f(ry);
        if (ay >= 1)  sh += hann_f(ry + 64);
        int ax = x >> 6, rx = x - (ax << 6);
        float sw = 0.0f;
        if (ax <= 10) sw += hann_f(rx);
        if (ax >= 1)  sw += hann_f(rx + 64);
        float v = out[idx] / (sh * sw + EPSF);
        out[idx] = powf(fmaxf(v, 0.0f) + EPSF, ig);
    }
}

extern "C" void kernel_launch(void* const* d_in, const int* in_sizes, int n_in,
                              void* d_out, int out_size, void* d_ws, size_t ws_size,
                              hipStream_t stream) {
    const float* x  = (const float*)d_in[0];
    const float* w1 = (const float*)d_in[1];
    const float* b1 = (const float*)d_in[2];
    const float* w2 = (const float*)d_in[3];
    const float* b2 = (const float*)d_in[4];
    const float* w3 = (const float*)d_in[5];
    const float* b3 = (const float*)d_in[6];
    const float* gp = (const float*)d_in[7];
    float* out = (float*)d_out;
    float* ws  = (float*)d_ws;

    hipMemsetAsync(d_out, 0, (size_t)out_size * sizeof(float), stream);
    int ntot = NB * NC * HH * HH;
    k_pow<<<4096, 256, 0, stream>>>(x, gp, ws + XLIN_OFF, ntot);
    k_basis<<<1, 256, 0, stream>>>(ws);
    k_mlp<<<NN, 64, 0, stream>>>(w1, b1, w2, b2, w3, b3, ws);
    k_psf<<<NN * NC, 128, 0, stream>>>(ws);
    dim3 cg(NB * NN * NC, 4);
    k_conv<<<cg, 256, 0, stream>>>(ws, out);
    k_final<<<4096, 256, 0, stream>>>(out, gp, ntot);
}

// Round 2
// 749.990 us; speedup vs baseline: 1.0309x; 1.0309x over previous
//
#include <hip/hip_runtime.h>
#include <math.h>

#define EPSF 1e-6f
#define NB   4
#define NC   3
#define HH   768
#define KS   31
#define KK   961
#define NHW  11
#define NN   121
#define NZ   14
#define HID  64

// workspace layout (float offsets)
#define XLIN_OFF  0
#define XLIN_SZ   (NB*NC*HH*HH)            // 7,077,888
#define BASIS_OFF (XLIN_OFF + XLIN_SZ)
#define MASK_OFF  (BASIS_OFF + 13456)      // basis needs 14*961=13454
#define COEF_OFF  (MASK_OFF + 964)         // mask needs 961
#define KERN_OFF  (COEF_OFF + 1696)        // coeffs need 121*14=1694
// kern needs 363*961 = 348,843 -> total ~29.8 MB

__device__ __forceinline__ float hann_f(int p) {
    return 0.5f * (1.0f - cosf(6.283185307179586f * (float)p / 128.0f));
}

__global__ void k_pow(const float* __restrict__ x, const float* __restrict__ gp,
                      float* __restrict__ y, int n) {
    float g = *gp;
    for (int i = blockIdx.x * blockDim.x + threadIdx.x; i < n; i += gridDim.x * blockDim.x)
        y[i] = powf(fmaxf(x[i], 0.0f) + EPSF, g);
}

// Zernike-like polynomial basis, bit-exact mask vs numpy linspace semantics.
__global__ void k_basis(float* __restrict__ ws) {
    __shared__ float red[256];
    __shared__ float srms[NZ];
    __shared__ float scnt;
    float* basis = ws + BASIS_OFF;
    float* mask  = ws + MASK_OFF;
    int tid = threadIdx.x;
    double lsq[NZ];
    #pragma unroll
    for (int z = 0; z < NZ; ++z) lsq[z] = 0.0;
    double lcnt = 0.0;
    for (int pix = tid; pix < KK; pix += 256) {
        int i = pix / 31, j = pix - i * 31;
        double x = (j == 30) ? 1.0 : (-1.0 + (double)j * (2.0 / 30.0));
        double y = (i == 30) ? 1.0 : (-1.0 + (double)i * (2.0 / 30.0));
        double r2 = x * x + y * y;
        float m = (r2 <= 1.0) ? 1.0f : 0.0f;
        mask[pix] = m;
        lcnt += (double)m;
        #pragma unroll
        for (int deg = 1; deg <= 4; ++deg) {
            #pragma unroll
            for (int ii = 0; ii <= deg; ++ii) {
                const int z = deg * (deg + 1) / 2 - 1 + ii;
                double px = 1.0, py = 1.0;
                #pragma unroll
                for (int t = 0; t < deg - ii; ++t) px *= x;
                #pragma unroll
                for (int t = 0; t < ii; ++t) py *= y;
                float bf = (float)(px * py) * m;
                basis[z * KK + pix] = bf;
                lsq[z] += (double)bf * (double)bf;
            }
        }
    }
    for (int q = 0; q < NZ + 1; ++q) {
        red[tid] = (q < NZ) ? (float)lsq[q] : (float)lcnt;
        __syncthreads();
        for (int s = 128; s > 0; s >>= 1) {
            if (tid < s) red[tid] += red[tid + s];
            __syncthreads();
        }
        if (tid == 0) { if (q < NZ) srms[q] = red[0]; else scnt = red[0]; }
        __syncthreads();
    }
    if (tid < NZ) srms[tid] = sqrtf(srms[tid] / scnt) + 1e-8f;
    __syncthreads();
    for (int pix = tid; pix < KK; pix += 256) {
        #pragma unroll
        for (int z = 0; z < NZ; ++z)
            basis[z * KK + pix] = basis[z * KK + pix] / srms[z];
    }
}

// 121 unique coords (batch-tiled in reference), one block of 64 per coord.
__global__ void k_mlp(const float* __restrict__ w1, const float* __restrict__ b1,
                      const float* __restrict__ w2, const float* __restrict__ b2,
                      const float* __restrict__ w3, const float* __restrict__ b3,
                      float* __restrict__ ws) {
    __shared__ float h1[HID], h2[HID];
    int n = blockIdx.x, t = threadIdx.x;
    int a = n / NHW, bw = n - a * NHW;
    float gy = (float)((((double)(a * 64)  + 64.0) / 768.0) * 2.0 - 1.0);
    float gx = (float)((((double)(bw * 64) + 64.0) / 768.0) * 2.0 - 1.0);
    h1[t] = tanhf(gy * w1[t] + gx * w1[HID + t] + b1[t]);
    __syncthreads();
    float acc2 = b2[t];
    for (int k = 0; k < HID; ++k) acc2 += h1[k] * w2[k * HID + t];
    h2[t] = tanhf(acc2);
    __syncthreads();
    if (t < NZ) {
        float acc3 = b3[t];
        for (int k = 0; k < HID; ++k) acc3 += h2[k] * w3[k * NZ + t];
        ws[COEF_OFF + n * NZ + t] = acc3;
    }
}

// One block per (n,c): phase -> field -> 31-pt row DFT -> col DFT -> |F|^2,
// normalize, write with fftshift+flip folded: kflip[u,v]=|F[(15-u)%31,(15-v)%31]|^2/sum
__global__ void k_psf(float* __restrict__ ws) {
    __shared__ float fre[KK], fim[KK], gre[KK], gim[KK], sS[KK];
    __shared__ float twc[KS], tws[KS], cf[NZ], red[128];
    int blk = blockIdx.x;
    int n = blk / 3, c = blk - n * 3;
    int tid = threadIdx.x;
    const float* basis = ws + BASIS_OFF;
    const float* mask  = ws + MASK_OFF;
    if (tid < NZ) cf[tid] = ws[COEF_OFF + n * NZ + tid];
    if (tid < KS) {
        float ang = -6.283185307179586f * (float)tid / 31.0f;
        float s, co;
        sincosf(ang, &s, &co);
        twc[tid] = co; tws[tid] = s;
    }
    const float wl = (c == 0) ? (0.53f / 0.61f) : ((c == 1) ? 1.0f : (0.53f / 0.47f));
    __syncthreads();
    for (int pix = tid; pix < KK; pix += 128) {
        float ph = 0.0f;
        #pragma unroll
        for (int z = 0; z < NZ; ++z) ph += cf[z] * basis[z * KK + pix];
        float ang = 6.283185307179586f * (wl * ph);
        float s, co;
        sincosf(ang, &s, &co);
        float m = mask[pix];
        fre[pix] = m * co;
        fim[pix] = m * s;
    }
    __syncthreads();
    for (int pix = tid; pix < KK; pix += 128) {
        int i = pix / 31, q = pix - i * 31;
        float ar = 0.0f, ai = 0.0f;
        int m = 0;
        const float* br = &fre[i * 31];
        const float* bi = &fim[i * 31];
        #pragma unroll
        for (int j = 0; j < 31; ++j) {
            float tc = twc[m], ts = tws[m];
            float xr = br[j], xi = bi[j];
            ar += xr * tc - xi * ts;
            ai += xr * ts + xi * tc;
            m += q; if (m >= 31) m -= 31;
        }
        gre[pix] = ar; gim[pix] = ai;
    }
    __syncthreads();
    float lsum = 0.0f;
    for (int pix = tid; pix < KK; pix += 128) {
        int p = pix / 31, q = pix - p * 31;
        float ar = 0.0f, ai = 0.0f;
        int m = 0;
        #pragma unroll
        for (int i2 = 0; i2 < 31; ++i2) {
            float tc = twc[m], ts = tws[m];
            float xr = gre[i2 * 31 + q], xi = gim[i2 * 31 + q];
            ar += xr * tc - xi * ts;
            ai += xr * ts + xi * tc;
            m += p; if (m >= 31) m -= 31;
        }
        float sv = ar * ar + ai * ai;
        sS[pix] = sv;
        lsum += sv;
    }
    red[tid] = lsum;
    __syncthreads();
    for (int s = 64; s > 0; s >>= 1) {
        if (tid < s) red[tid] += red[tid + s];
        __syncthreads();
    }
    float tot = red[0] + EPSF;
    float* kern = ws + KERN_OFF + (n * 3 + c) * KK;
    for (int pix = tid; pix < KK; pix += 128) {
        int u = pix / 31, v = pix - u * 31;
        int iu = 15 - u; if (iu < 0) iu += 31;
        int iv = 15 - v; if (iv < 0) iv += 31;
        kern[pix] = sS[iu * 31 + iv] / tot;
    }
}

// Hot kernel, R2: LDS-pipe pressure halved per FMA.
// Block tile 64 rows x 128 cols (4 waves = 2 row-groups x 2 col-groups),
// wave tile 32 rows x 64 cols (lane = column -> stride-1 conflict-free LDS).
// Per v-step per wave: 62 patch reads + 31 kern broadcasts feed 992 FMAs
// (10.7 FMA/read vs 6.4 in R1; CU LDS-pipe demand ~= VALU issue -> VALU-bound).
// LDS: sP 94x160x4 = 60160 B + sK 3844 B = ~64 KB -> 2 blocks/CU, 8 waves/CU.
__global__ __launch_bounds__(256) void k_conv(const float* __restrict__ ws,
                                              float* __restrict__ out) {
    __shared__ float sK[KK];
    __shared__ float sP[94][160];
    int unit = blockIdx.x;
    int rb = blockIdx.y;
    int bn = unit / 3, c = unit - bn * 3;
    int b = bn / NN, n = bn - b * NN;
    int a = n / NHW, bw = n - a * NHW;
    int tid = threadIdx.x;
    const float* kern = ws + KERN_OFF + (n * 3 + c) * KK;
    for (int i = tid; i < KK; i += 256) sK[i] = kern[i];
    const float* xl = ws + XLIN_OFF + (b * 3 + c) * (HH * HH);
    int row0 = rb * 64;   // output-row base; LDS slab = zero-padded patch rows row0-15..row0+78
    for (int idx = tid; idx < 94 * 158; idx += 256) {
        int s = idx / 158, pc = idx - s * 158;
        int pi = row0 + s - 15;   // patch-local row (zero-pad outside [0,128))
        int pj = pc - 15;
        float v = 0.0f;
        if (pi >= 0 && pi < 128 && pj >= 0 && pj < 128)
            v = xl[(a * 64 + pi) * HH + (bw * 64 + pj)];
        sP[s][pc] = v;
    }
    __syncthreads();
    int wave = tid >> 6, lane = tid & 63;
    int wr = (wave >> 1) * 32;    // wave's output-row offset within block (0|32)
    int c0 = (wave & 1) * 64;     // wave's column base (0|64)
    int col = c0 + lane;
    float acc[32];
    #pragma unroll
    for (int r = 0; r < 32; ++r) acc[r] = 0.0f;
    const float* pbase = &sP[wr][col];
    #pragma unroll 1
    for (int v = 0; v < 31; ++v) {
        float w[62];
        #pragma unroll
        for (int s = 0; s < 62; ++s) w[s] = pbase[s * 160 + v];
        #pragma unroll
        for (int u = 0; u < 31; ++u) {
            float kv = sK[u * 31 + v];   // wave-uniform broadcast
            #pragma unroll
            for (int r = 0; r < 32; ++r) acc[r] += kv * w[u + r];
        }
    }
    float wcol = hann_f(col);
    float* ob = out + (b * 3 + c) * (HH * HH) + (a * 64) * HH + bw * 64 + col;
    #pragma unroll
    for (int r = 0; r < 32; ++r) {
        int i = row0 + wr + r;
        atomicAdd(ob + i * HH, acc[r] * hann_f(i) * wcol);
    }
}

// Overlap-add normalization (norm is separable: sh[y]*sw[x]) + inverse gamma.
__global__ void k_final(float* __restrict__ out, const float* __restrict__ gp, int ntot) {
    float ig = 1.0f / (*gp);
    for (int idx = blockIdx.x * blockDim.x + threadIdx.x; idx < ntot;
         idx += gridDim.x * blockDim.x) {
        int x = idx % HH;
        int y = (idx / HH) % HH;
        int ay = y >> 6, ry = y - (ay << 6);
        float sh = 0.0f;
        if (ay <= 10) sh += hann_f(ry);
        if (ay >= 1)  sh += hann_f(ry + 64);
        int ax = x >> 6, rx = x - (ax << 6);
        float sw = 0.0f;
        if (ax <= 10) sw += hann_f(rx);
        if (ax >= 1)  sw += hann_f(rx + 64);
        float v = out[idx] / (sh * sw + EPSF);
        out[idx] = powf(fmaxf(v, 0.0f) + EPSF, ig);
    }
}

extern "C" void kernel_launch(void* const* d_in, const int* in_sizes, int n_in,
                              void* d_out, int out_size, void* d_ws, size_t ws_size,
                              hipStream_t stream) {
    const float* x  = (const float*)d_in[0];
    const float* w1 = (const float*)d_in[1];
    const float* b1 = (const float*)d_in[2];
    const float* w2 = (const float*)d_in[3];
    const float* b2 = (const float*)d_in[4];
    const float* w3 = (const float*)d_in[5];
    const float* b3 = (const float*)d_in[6];
    const float* gp = (const float*)d_in[7];
    float* out = (float*)d_out;
    float* ws  = (float*)d_ws;

    hipMemsetAsync(d_out, 0, (size_t)out_size * sizeof(float), stream);
    int ntot = NB * NC * HH * HH;
    k_pow<<<4096, 256, 0, stream>>>(x, gp, ws + XLIN_OFF, ntot);
    k_basis<<<1, 256, 0, stream>>>(ws);
    k_mlp<<<NN, 64, 0, stream>>>(w1, b1, w2, b2, w3, b3, ws);
    k_psf<<<NN * NC, 128, 0, stream>>>(ws);
    dim3 cg(NB * NN * NC, 2);
    k_conv<<<cg, 256, 0, stream>>>(ws, out);
    k_final<<<4096, 256, 0, stream>>>(out, gp, ntot);
}